// Round 8
// baseline (246.825 us; speedup 1.0000x reference)
//
#include <hip/hip_runtime.h>
#include <math.h>

#define BB 2
#define VV 5
#define CC 32
#define HH 128
#define WW 160
#define DD 32
#define HWp (HH*WW)          // 20480
#define NV (VV-1)            // 4 src views
#define PXW 8                // pixels per (1-wave) block; divides WW

// ---- workspace float offsets ----
#define OFF_RT   0                                   // B*NV*12 = 96
#define OFF_PRM  96                                  // 177 net params
#define OFF_FEAT 512                                 // V*B*HW*C = 6,553,600
#define OFF_SIM  (OFF_FEAT + VV*BB*HWp*CC)           // B*D*HW similarity

// ---- output float offsets (depth, conf, prob, cost_reg, view_weights) ----
#define OUT_DEPTH 0
#define OUT_CONF  (BB*HWp)
#define OUT_PROB  (2*BB*HWp)
#define OUT_COST  (OUT_PROB + BB*DD*HWp)
#define OUT_VW    (OUT_COST + BB*DD*HWp)

// ---------------- setup: projection matrices + folded BN params ----------------
__device__ void build_proj(const float* proj, int b, int v, double M[4][4]) {
    const float* E = proj + (((b*VV + v)*2 + 0)*16);
    const float* K = proj + (((b*VV + v)*2 + 1)*16);
    for (int r = 0; r < 3; r++)
        for (int c = 0; c < 4; c++) {
            double s = 0.0;
            for (int k = 0; k < 3; k++) s += (double)K[r*4+k] * (double)E[k*4+c];
            M[r][c] = s;
        }
    for (int c = 0; c < 4; c++) M[3][c] = (double)E[12+c];
}

__device__ void inv4(const double M[4][4], double out[4][4]) {
    double a[4][8];
    for (int i = 0; i < 4; i++)
        for (int j = 0; j < 4; j++) { a[i][j] = M[i][j]; a[i][4+j] = (i == j) ? 1.0 : 0.0; }
    for (int col = 0; col < 4; col++) {
        int piv = col; double best = fabs(a[col][col]);
        for (int r = col+1; r < 4; r++) if (fabs(a[r][col]) > best) { best = fabs(a[r][col]); piv = r; }
        if (piv != col) for (int j = 0; j < 8; j++) { double t = a[col][j]; a[col][j] = a[piv][j]; a[piv][j] = t; }
        double dinv = 1.0 / a[col][col];
        for (int j = 0; j < 8; j++) a[col][j] *= dinv;
        for (int r = 0; r < 4; r++) {
            if (r == col) continue;
            double f = a[r][col];
            for (int j = 0; j < 8; j++) a[r][j] -= f * a[col][j];
        }
    }
    for (int i = 0; i < 4; i++) for (int j = 0; j < 4; j++) out[i][j] = a[i][4+j];
}

__global__ void setup_kernel(const float* __restrict__ proj,
    const float* __restrict__ w0, const float* __restrict__ g0, const float* __restrict__ b0,
    const float* __restrict__ m0, const float* __restrict__ v0,
    const float* __restrict__ w1, const float* __restrict__ g1, const float* __restrict__ b1,
    const float* __restrict__ m1, const float* __restrict__ v1,
    const float* __restrict__ w2, const float* __restrict__ b2,
    float* __restrict__ ws) {
    if (threadIdx.x != 0 || blockIdx.x != 0) return;
    for (int b = 0; b < BB; b++) {
        double refM[4][4], inv[4][4];
        build_proj(proj, b, 0, refM);
        inv4(refM, inv);
        for (int v = 1; v < VV; v++) {
            double S[4][4]; build_proj(proj, b, v, S);
            float* rt = ws + OFF_RT + (b*NV + (v-1))*12;
            for (int r = 0; r < 3; r++) {
                for (int c = 0; c < 3; c++) {
                    double s = 0.0;
                    for (int k = 0; k < 4; k++) s += S[r][k] * inv[k][c];
                    rt[r*3 + c] = (float)s;
                }
                double s = 0.0;
                for (int k = 0; k < 4; k++) s += S[r][k] * inv[k][3];
                rt[9 + r] = (float)s;
            }
        }
    }
    float* prm = ws + OFF_PRM;
    for (int o = 0; o < 16; o++) {
        float sc = g0[o] / sqrtf(v0[o] + 1e-5f);
        prm[o]      = w0[o] * sc;
        prm[16 + o] = b0[o] - m0[o] * sc;
    }
    for (int q = 0; q < 8; q++) {
        float sc = g1[q] / sqrtf(v1[q] + 1e-5f);
        for (int o = 0; o < 16; o++) prm[32 + q*16 + o] = w1[q*16 + o] * sc;
        prm[160 + q] = b1[q] - m1[q] * sc;
        prm[168 + q] = w2[q];
    }
    prm[176] = b2[0];
}

// ---------------- transpose features to (V,B,H,W,C) ----------------
__global__ __launch_bounds__(256) void transpose_kernel(const float* __restrict__ fea,
                                                        float* __restrict__ featT) {
    int t = blockIdx.x*256 + threadIdx.x;        // V*B*H*W
    int w = t % WW;
    int h = (t / WW) % HH;
    int b = (t / (WW*HH)) % BB;
    int v = t / (WW*HH*BB);
    const float* src = fea + (size_t)((v*BB + b)*CC) * HWp + h*WW + w;
    float* dst = featT + (size_t)((v*BB + b)*HWp + h*WW + w) * CC;
    #pragma unroll
    for (int c = 0; c < CC; c += 4) {
        float4 q;
        q.x = src[(c+0)*HWp];
        q.y = src[(c+1)*HWp];
        q.z = src[(c+2)*HWp];
        q.w = src[(c+3)*HWp];
        *reinterpret_cast<float4*>(dst + c) = q;
    }
}

__device__ __forceinline__ float half_max(float v) {
    v = fmaxf(v, __shfl_xor(v, 1));
    v = fmaxf(v, __shfl_xor(v, 2));
    v = fmaxf(v, __shfl_xor(v, 4));
    v = fmaxf(v, __shfl_xor(v, 8));
    v = fmaxf(v, __shfl_xor(v, 16));
    return v;
}

__device__ __forceinline__ float dot4(float4 a, float4 r) {
    return fmaf(a.w, r.w, fmaf(a.z, r.z, fmaf(a.y, r.y, a.x*r.x)));
}

// MLP up to the final pre-sigmoid activation h2 (sigmoid applied after d-max,
// valid since sigmoid is monotone).
__device__ __forceinline__ float mlp_h2(const float* __restrict__ prm, float s) {
    float h0[16];
    #pragma unroll
    for (int o = 0; o < 16; o++) h0[o] = fmaxf(prm[o]*s + prm[16+o], 0.f);
    float h2 = prm[176];
    #pragma unroll
    for (int q = 0; q < 8; q++) {
        float a1 = prm[160+q];
        #pragma unroll
        for (int o = 0; o < 16; o++) a1 += prm[32+q*16+o]*h0[o];
        h2 += prm[168+q]*fmaxf(a1, 0.f);
    }
    return h2;
}

// ---------------- fused warp + sim + MLP + view aggregation ----------------
// ONE WAVE per block, no __syncthreads. Lane = (chan-half sub=lane>>5, depth
// dB=lane&31). Per pixel: dot-first sim, full-wave shfl_xor(32) reduce; sims
// for a pixel PAIR stay in registers, then inline phase B (lane = (pixel p2,
// depth d2)): MLP + d-max + sigmoid + aggregation.
__global__ __launch_bounds__(64) void fused_sim_kernel(
    const float* __restrict__ featT, const float* __restrict__ rtAll,
    const float* __restrict__ prm, const float* __restrict__ depthv,
    float* __restrict__ simout, float* __restrict__ out) {
    __shared__ float depthL[DD][PXW+1];   // 1.15 KB; padded: conflict-free b32 reads

    int lane = threadIdx.x;   // 0..63
    int dB   = lane & 31;     // depth
    int sub  = lane >> 5;     // channel half: channels sub*16 .. sub*16+15
    int sub16 = sub*16;
    int b = blockIdx.y;
    int pbase = blockIdx.x * PXW;          // row-aligned (PXW | WW)
    int hi  = pbase / WW;
    int wi0 = pbase % WW;
    float fy = (float)hi;

    // stage depth tile (32 d x PXW) — same-wave produce/consume, no barrier
    {
        int d = lane >> 1, kq = (lane & 1) * 4;
        float4 q = *reinterpret_cast<const float4*>(&depthv[(b*DD + d)*HWp + pbase + kq]);
        depthL[d][kq+0] = q.x;
        depthL[d][kq+1] = q.y;
        depthL[d][kq+2] = q.z;
        depthL[d][kq+3] = q.w;
    }

    // wave-uniform projection coefficients (compiler -> SGPR)
    float rc[NV][12];
    #pragma unroll
    for (int v = 0; v < NV; v++)
        #pragma unroll
        for (int j = 0; j < 12; j++)
            rc[v][j] = rtAll[(b*NV + v)*12 + j];
    float bx0[NV], by0[NV], bz0[NV];
    const float* vb[NV];
    #pragma unroll
    for (int v = 0; v < NV; v++) {
        bx0[v] = fmaf((float)wi0, rc[v][0], fmaf(fy, rc[v][1], rc[v][2]));
        by0[v] = fmaf((float)wi0, rc[v][3], fmaf(fy, rc[v][4], rc[v][5]));
        bz0[v] = fmaf((float)wi0, rc[v][6], fmaf(fy, rc[v][7], rc[v][8]));
        vb[v]  = featT + (size_t)(((v+1)*BB + b)*HWp)*CC;
    }

    int p2 = lane >> 5;       // phase-B pixel parity (= sub)
    float simP0[NV], simP1[NV];

    for (int pair = 0; pair < PXW/2; pair++) {
        // ---- phase A: two pixels, sims into registers ----
        #pragma unroll
        for (int half = 0; half < 2; half++) {
            int k = pair*2 + half;
            int p = pbase + k;
            float fk = (float)k;
            float depth = depthL[dB][k];
            const float* refp = featT + (size_t)(b*HWp + p)*CC + sub16;
            float4 r0 = *reinterpret_cast<const float4*>(refp);
            float4 r1 = *reinterpret_cast<const float4*>(refp + 4);
            float4 r2 = *reinterpret_cast<const float4*>(refp + 8);
            float4 r3 = *reinterpret_cast<const float4*>(refp + 12);

            #pragma unroll
            for (int v = 0; v < NV; v++) {
                float bx = fmaf(fk, rc[v][0], bx0[v]);
                float by = fmaf(fk, rc[v][3], by0[v]);
                float bz = fmaf(fk, rc[v][6], bz0[v]);
                float px = fmaf(bx, depth, rc[v][9]);
                float py = fmaf(by, depth, rc[v][10]);
                float pz = fmaf(bz, depth, rc[v][11]);
                float zi = __builtin_amdgcn_rcpf(pz);
                float sx = px * zi, sy = py * zi;
                float x0f = floorf(sx), y0f = floorf(sy);
                float wx1 = sx - x0f, wy1 = sy - y0f;
                float wx0 = 1.f - wx1, wy0 = 1.f - wy1;
                int xi0 = (int)x0f, yi0 = (int)y0f;
                int xi1 = xi0 + 1,  yi1 = yi0 + 1;
                float ax0 = ((unsigned)xi0 < (unsigned)WW) ? wx0 : 0.f;
                float ax1 = ((unsigned)xi1 < (unsigned)WW) ? wx1 : 0.f;
                float ay0 = ((unsigned)yi0 < (unsigned)HH) ? wy0 : 0.f;
                float ay1 = ((unsigned)yi1 < (unsigned)HH) ? wy1 : 0.f;
                int xc0 = min(max(xi0, 0), WW-1);
                int xc1 = min(max(xi1, 0), WW-1);
                int yc0 = min(max(yi0, 0), HH-1);
                int yc1 = min(max(yi1, 0), HH-1);
                int r0i = yc0*WW, r1i = yc1*WW;
                float w00 = ax0*ay0, w01 = ax1*ay0, w10 = ax0*ay1, w11 = ax1*ay1;

                const float* tp;
                float4 a0, a1, a2, a3;
                float acc;

                tp = vb[v] + (((r0i + xc0) << 5) + sub16);
                a0 = *reinterpret_cast<const float4*>(tp);
                a1 = *reinterpret_cast<const float4*>(tp + 4);
                a2 = *reinterpret_cast<const float4*>(tp + 8);
                a3 = *reinterpret_cast<const float4*>(tp + 12);
                acc = w00 * (dot4(a0,r0) + dot4(a1,r1) + dot4(a2,r2) + dot4(a3,r3));

                tp = vb[v] + (((r0i + xc1) << 5) + sub16);
                a0 = *reinterpret_cast<const float4*>(tp);
                a1 = *reinterpret_cast<const float4*>(tp + 4);
                a2 = *reinterpret_cast<const float4*>(tp + 8);
                a3 = *reinterpret_cast<const float4*>(tp + 12);
                acc = fmaf(w01, dot4(a0,r0) + dot4(a1,r1) + dot4(a2,r2) + dot4(a3,r3), acc);

                tp = vb[v] + (((r1i + xc0) << 5) + sub16);
                a0 = *reinterpret_cast<const float4*>(tp);
                a1 = *reinterpret_cast<const float4*>(tp + 4);
                a2 = *reinterpret_cast<const float4*>(tp + 8);
                a3 = *reinterpret_cast<const float4*>(tp + 12);
                acc = fmaf(w10, dot4(a0,r0) + dot4(a1,r1) + dot4(a2,r2) + dot4(a3,r3), acc);

                tp = vb[v] + (((r1i + xc1) << 5) + sub16);
                a0 = *reinterpret_cast<const float4*>(tp);
                a1 = *reinterpret_cast<const float4*>(tp + 4);
                a2 = *reinterpret_cast<const float4*>(tp + 8);
                a3 = *reinterpret_cast<const float4*>(tp + 12);
                acc = fmaf(w11, dot4(a0,r0) + dot4(a1,r1) + dot4(a2,r2) + dot4(a3,r3), acc);

                acc += __shfl_xor(acc, 32);          // combine channel halves
                float s = acc * (1.f/(float)CC);
                if (half == 0) simP0[v] = s; else simP1[v] = s;
            }
        }

        // ---- phase B inline: lane = (pixel p2, depth d2=dB) ----
        float s0 = p2 ? simP1[0] : simP0[0];
        float s1 = p2 ? simP1[1] : simP0[1];
        float s2 = p2 ? simP1[2] : simP0[2];
        float s3 = p2 ? simP1[3] : simP0[3];

        float m0 = half_max(mlp_h2(prm, s0));
        float m1 = half_max(mlp_h2(prm, s1));
        float m2 = half_max(mlp_h2(prm, s2));
        float m3 = half_max(mlp_h2(prm, s3));
        float vw0 = 1.f/(1.f + __expf(-m0));
        float vw1 = 1.f/(1.f + __expf(-m1));
        float vw2 = 1.f/(1.f + __expf(-m2));
        float vw3 = 1.f/(1.f + __expf(-m3));

        int pOut = pbase + pair*2 + p2;
        if (dB == 0) out[OUT_VW + (b*NV + 0)*HWp + pOut] = vw0;
        if (dB == 1) out[OUT_VW + (b*NV + 1)*HWp + pOut] = vw1;
        if (dB == 2) out[OUT_VW + (b*NV + 2)*HWp + pOut] = vw2;
        if (dB == 3) out[OUT_VW + (b*NV + 3)*HWp + pOut] = vw3;

        float wsum = 1e-5f + vw0 + vw1 + vw2 + vw3;
        float ssum = s0*vw0 + s1*vw1 + s2*vw2 + s3*vw3;
        simout[(b*DD + dB)*HWp + pOut] = ssum / wsum;
    }
}

// ---------------- 3x3x3 conv (SAME, zero pad) ----------------
__global__ __launch_bounds__(256) void conv_kernel(
    const float* __restrict__ sim, const float* __restrict__ rw,
    const float* __restrict__ rb, float* __restrict__ out) {
    int g = blockIdx.x*256 + threadIdx.x;   // B*D*HW
    int p = g % HWp;
    int dt = g / HWp;
    int d = dt % DD, b = dt / DD;
    int wi = p % WW, hi = p / WW;
    float acc = rb[0];
    #pragma unroll
    for (int kd = 0; kd < 3; kd++) {
        int dd2 = d + kd - 1;
        if (dd2 < 0 || dd2 >= DD) continue;
        #pragma unroll
        for (int kh = 0; kh < 3; kh++) {
            int hh2 = hi + kh - 1;
            if (hh2 < 0 || hh2 >= HH) continue;
            #pragma unroll
            for (int kw = 0; kw < 3; kw++) {
                int ww2 = wi + kw - 1;
                if (ww2 < 0 || ww2 >= WW) continue;
                acc += rw[(kd*3 + kh)*3 + kw] * sim[((b*DD + dd2)*HH + hh2)*WW + ww2];
            }
        }
    }
    out[OUT_COST + g] = acc;
}

// ---------------- softmax over D + argmax -> depth/conf/prob ----------------
__global__ __launch_bounds__(256) void softmax_kernel(
    const float* __restrict__ depthv, float* __restrict__ out) {
    int g = blockIdx.x*256 + threadIdx.x;   // B*HW
    int b = g / HWp, p = g % HWp;
    float c[DD];
    #pragma unroll
    for (int d = 0; d < DD; d++) c[d] = out[OUT_COST + (b*DD + d)*HWp + p];
    float m = c[0]; int bi = 0;
    #pragma unroll
    for (int d = 1; d < DD; d++) { if (c[d] > m) { m = c[d]; bi = d; } }
    float e[DD]; float sum = 0.f;
    #pragma unroll
    for (int d = 0; d < DD; d++) { e[d] = expf(c[d] - m); sum += e[d]; }
    float inv = 1.f / sum;
    #pragma unroll
    for (int d = 0; d < DD; d++) out[OUT_PROB + (b*DD + d)*HWp + p] = e[d] * inv;
    out[OUT_DEPTH + g] = depthv[(b*DD + bi)*HWp + p];
    out[OUT_CONF + g]  = inv;
}

extern "C" void kernel_launch(void* const* d_in, const int* in_sizes, int n_in,
                              void* d_out, int out_size, void* d_ws, size_t ws_size,
                              hipStream_t stream) {
    const float* features = (const float*)d_in[0];
    const float* proj     = (const float*)d_in[1];
    const float* depthv   = (const float*)d_in[2];
    const float* w0 = (const float*)d_in[4];
    const float* g0 = (const float*)d_in[5];
    const float* b0 = (const float*)d_in[6];
    const float* m0 = (const float*)d_in[7];
    const float* v0 = (const float*)d_in[8];
    const float* w1 = (const float*)d_in[9];
    const float* g1 = (const float*)d_in[10];
    const float* b1 = (const float*)d_in[11];
    const float* m1 = (const float*)d_in[12];
    const float* v1 = (const float*)d_in[13];
    const float* w2 = (const float*)d_in[14];
    const float* b2 = (const float*)d_in[15];
    const float* rw = (const float*)d_in[16];
    const float* rb = (const float*)d_in[17];
    float* out = (float*)d_out;
    float* ws  = (float*)d_ws;

    setup_kernel<<<1, 1, 0, stream>>>(proj, w0, g0, b0, m0, v0, w1, g1, b1, m1, v1, w2, b2, ws);
    transpose_kernel<<<VV*BB*HWp/256, 256, 0, stream>>>(features, ws + OFF_FEAT);

    fused_sim_kernel<<<dim3(HWp/PXW, BB), 64, 0, stream>>>(
        ws + OFF_FEAT, ws + OFF_RT, ws + OFF_PRM, depthv,
        ws + OFF_SIM, out);

    conv_kernel<<<BB*DD*HWp/256, 256, 0, stream>>>(ws + OFF_SIM, rw, rb, out);
    softmax_kernel<<<BB*HWp/256, 256, 0, stream>>>(depthv, out);
}

// Round 9
// 148.051 us; speedup vs baseline: 1.6672x; 1.6672x over previous
//
#include <hip/hip_runtime.h>
#include <math.h>

#define BB 2
#define VV 5
#define CC 32
#define HH 128
#define WW 160
#define DD 32
#define HWp (HH*WW)          // 20480
#define NV (VV-1)            // 4 src views
#define PX 16                // pixels per block (divides WW)

// ---- workspace float offsets ----
#define OFF_RT   0                                   // B*NV*12 = 96
#define OFF_PRM  96                                  // 177 net params
#define OFF_FEAT 512                                 // V*B*HW*C = 6,553,600
#define OFF_SIM  (OFF_FEAT + VV*BB*HWp*CC)           // B*D*HW similarity

// ---- output float offsets (depth, conf, prob, cost_reg, view_weights) ----
#define OUT_DEPTH 0
#define OUT_CONF  (BB*HWp)
#define OUT_PROB  (2*BB*HWp)
#define OUT_COST  (OUT_PROB + BB*DD*HWp)
#define OUT_VW    (OUT_COST + BB*DD*HWp)

// ---------------- setup: projection matrices + folded BN params ----------------
__device__ void build_proj(const float* proj, int b, int v, double M[4][4]) {
    const float* E = proj + (((b*VV + v)*2 + 0)*16);
    const float* K = proj + (((b*VV + v)*2 + 1)*16);
    for (int r = 0; r < 3; r++)
        for (int c = 0; c < 4; c++) {
            double s = 0.0;
            for (int k = 0; k < 3; k++) s += (double)K[r*4+k] * (double)E[k*4+c];
            M[r][c] = s;
        }
    for (int c = 0; c < 4; c++) M[3][c] = (double)E[12+c];
}

__device__ void inv4(const double M[4][4], double out[4][4]) {
    double a[4][8];
    for (int i = 0; i < 4; i++)
        for (int j = 0; j < 4; j++) { a[i][j] = M[i][j]; a[i][4+j] = (i == j) ? 1.0 : 0.0; }
    for (int col = 0; col < 4; col++) {
        int piv = col; double best = fabs(a[col][col]);
        for (int r = col+1; r < 4; r++) if (fabs(a[r][col]) > best) { best = fabs(a[r][col]); piv = r; }
        if (piv != col) for (int j = 0; j < 8; j++) { double t = a[col][j]; a[col][j] = a[piv][j]; a[piv][j] = t; }
        double dinv = 1.0 / a[col][col];
        for (int j = 0; j < 8; j++) a[col][j] *= dinv;
        for (int r = 0; r < 4; r++) {
            if (r == col) continue;
            double f = a[r][col];
            for (int j = 0; j < 8; j++) a[r][j] -= f * a[col][j];
        }
    }
    for (int i = 0; i < 4; i++) for (int j = 0; j < 4; j++) out[i][j] = a[i][4+j];
}

__global__ void setup_kernel(const float* __restrict__ proj,
    const float* __restrict__ w0, const float* __restrict__ g0, const float* __restrict__ b0,
    const float* __restrict__ m0, const float* __restrict__ v0,
    const float* __restrict__ w1, const float* __restrict__ g1, const float* __restrict__ b1,
    const float* __restrict__ m1, const float* __restrict__ v1,
    const float* __restrict__ w2, const float* __restrict__ b2,
    float* __restrict__ ws) {
    if (threadIdx.x != 0 || blockIdx.x != 0) return;
    for (int b = 0; b < BB; b++) {
        double refM[4][4], inv[4][4];
        build_proj(proj, b, 0, refM);
        inv4(refM, inv);
        for (int v = 1; v < VV; v++) {
            double S[4][4]; build_proj(proj, b, v, S);
            float* rt = ws + OFF_RT + (b*NV + (v-1))*12;
            for (int r = 0; r < 3; r++) {
                for (int c = 0; c < 3; c++) {
                    double s = 0.0;
                    for (int k = 0; k < 4; k++) s += S[r][k] * inv[k][c];
                    rt[r*3 + c] = (float)s;
                }
                double s = 0.0;
                for (int k = 0; k < 4; k++) s += S[r][k] * inv[k][3];
                rt[9 + r] = (float)s;
            }
        }
    }
    float* prm = ws + OFF_PRM;
    for (int o = 0; o < 16; o++) {
        float sc = g0[o] / sqrtf(v0[o] + 1e-5f);
        prm[o]      = w0[o] * sc;
        prm[16 + o] = b0[o] - m0[o] * sc;
    }
    for (int q = 0; q < 8; q++) {
        float sc = g1[q] / sqrtf(v1[q] + 1e-5f);
        for (int o = 0; o < 16; o++) prm[32 + q*16 + o] = w1[q*16 + o] * sc;
        prm[160 + q] = b1[q] - m1[q] * sc;
        prm[168 + q] = w2[q];
    }
    prm[176] = b2[0];
}

// ---------------- transpose features to (V,B,H,W,C) ----------------
__global__ __launch_bounds__(256) void transpose_kernel(const float* __restrict__ fea,
                                                        float* __restrict__ featT) {
    int t = blockIdx.x*256 + threadIdx.x;        // V*B*H*W
    int w = t % WW;
    int h = (t / WW) % HH;
    int b = (t / (WW*HH)) % BB;
    int v = t / (WW*HH*BB);
    const float* src = fea + (size_t)((v*BB + b)*CC) * HWp + h*WW + w;
    float* dst = featT + (size_t)((v*BB + b)*HWp + h*WW + w) * CC;
    #pragma unroll
    for (int c = 0; c < CC; c += 4) {
        float4 q;
        q.x = src[(c+0)*HWp];
        q.y = src[(c+1)*HWp];
        q.z = src[(c+2)*HWp];
        q.w = src[(c+3)*HWp];
        *reinterpret_cast<float4*>(dst + c) = q;
    }
}

__device__ __forceinline__ float half_max(float v) {
    v = fmaxf(v, __shfl_xor(v, 1));
    v = fmaxf(v, __shfl_xor(v, 2));
    v = fmaxf(v, __shfl_xor(v, 4));
    v = fmaxf(v, __shfl_xor(v, 8));
    v = fmaxf(v, __shfl_xor(v, 16));
    return v;
}

// MLP up to the final pre-sigmoid activation h2 (sigmoid applied after d-max,
// valid since sigmoid is monotone).
__device__ __forceinline__ float mlp_h2(const float* __restrict__ prm, float s) {
    float h0[16];
    #pragma unroll
    for (int o = 0; o < 16; o++) h0[o] = fmaxf(prm[o]*s + prm[16+o], 0.f);
    float h2 = prm[176];
    #pragma unroll
    for (int q = 0; q < 8; q++) {
        float a1 = prm[160+q];
        #pragma unroll
        for (int o = 0; o < 16; o++) a1 += prm[32+q*16+o]*h0[o];
        h2 += prm[168+q]*fmaxf(a1, 0.f);
    }
    return h2;
}

// ---------------- fused warp + sim + MLP + view aggregation ----------------
// block = 256 threads. Phase A: thread = (pixel-parity kk=t>>7, depth d=(t>>2)&31,
// chan-octet sub=t&3); 2 pixels in flight, 4 threads/sim (8 channels each).
// Near-integer sy is snapped (<=1e-4 px change); the zero-weight tap row is
// skipped (wave-uniform for this geometry -> half the tap lines + FMAs).
// Phase B: thread=(pixel,d): MLP + d-max + sigmoid + aggregate across 4 views.
__global__ __launch_bounds__(256) void fused_sim_kernel(
    const float* __restrict__ featT, const float* __restrict__ rtAll,
    const float* __restrict__ prm, const float* __restrict__ depthv,
    float* __restrict__ simout, float* __restrict__ out) {
    __shared__ float simL[NV][DD][PX+1];    // padded: conflict-free
    __shared__ float depthL[DD][PX+1];

    int t = threadIdx.x;
    int sub = t & 3;          // channel octet: channels sub*8 .. sub*8+7
    int dB  = (t >> 2) & 31;  // depth
    int kk  = t >> 7;         // pixel parity (0/1)
    int b = blockIdx.y;
    int pbase = blockIdx.x * PX;            // row-aligned segment (PX | WW)
    int hi  = pbase / WW;
    int wi0 = pbase % WW;
    float fy = (float)hi;
    int sub8 = sub*8;

    // stage depth tile (32 d x PX)
    {
        int d = t >> 4, k = t & 15;
        depthL[d][k]      = depthv[(b*DD + d)*HWp + pbase + k];
        depthL[d+16][k]   = depthv[(b*DD + d+16)*HWp + pbase + k];
    }
    __syncthreads();

    // wave-uniform projection coefficients
    float rc[NV][12];
    #pragma unroll
    for (int v = 0; v < NV; v++)
        #pragma unroll
        for (int j = 0; j < 12; j++)
            rc[v][j] = rtAll[(b*NV + v)*12 + j];
    // per-view row bases + uniform view feature base pointers
    float bx0[NV], by0[NV], bz0[NV];
    const float* vb[NV];
    #pragma unroll
    for (int v = 0; v < NV; v++) {
        bx0[v] = fmaf((float)wi0, rc[v][0], fmaf(fy, rc[v][1], rc[v][2]));
        by0[v] = fmaf((float)wi0, rc[v][3], fmaf(fy, rc[v][4], rc[v][5]));
        bz0[v] = fmaf((float)wi0, rc[v][6], fmaf(fy, rc[v][7], rc[v][8]));
        vb[v]  = featT + (size_t)(((v+1)*BB + b)*HWp)*CC;
    }

    #pragma unroll 2
    for (int j = 0; j < PX/2; j++) {
        int kpix = j*2 + kk;
        int p = pbase + kpix;
        float fk = (float)kpix;
        float depth = depthL[dB][kpix];
        const float* refp = featT + (size_t)(b*HWp + p)*CC + sub8;
        float4 rva = *reinterpret_cast<const float4*>(refp);
        float4 rvb = *reinterpret_cast<const float4*>(refp + 4);

        #pragma unroll
        for (int v = 0; v < NV; v++) {
            float bx = fmaf(fk, rc[v][0], bx0[v]);
            float by = fmaf(fk, rc[v][3], by0[v]);
            float bz = fmaf(fk, rc[v][6], bz0[v]);
            float px = fmaf(bx, depth, rc[v][9]);
            float py = fmaf(by, depth, rc[v][10]);
            float pz = fmaf(bz, depth, rc[v][11]);
            float zi = __builtin_amdgcn_rcpf(pz);
            float sx = px * zi, sy = py * zi;
            // snap near-integer sample coords (error <= 1e-4 px, way below tol)
            float sny = rintf(sy);
            sy = (fabsf(sy - sny) < 1e-4f) ? sny : sy;
            float x0f = floorf(sx), y0f = floorf(sy);
            float wx1 = sx - x0f, wy1 = sy - y0f;
            float wx0 = 1.f - wx1, wy0 = 1.f - wy1;
            int xi0 = (int)x0f, yi0 = (int)y0f;
            int xi1 = xi0 + 1,  yi1 = yi0 + 1;
            float ax0 = ((unsigned)xi0 < WW) ? wx0 : 0.f;
            float ax1 = ((unsigned)xi1 < WW) ? wx1 : 0.f;
            float ay0 = ((unsigned)yi0 < HH) ? wy0 : 0.f;
            float ay1 = ((unsigned)yi1 < HH) ? wy1 : 0.f;
            int xc0 = min(max(xi0, 0), WW-1);
            int xc1 = min(max(xi1, 0), WW-1);
            int yc0 = min(max(yi0, 0), HH-1);
            float w00 = ax0*ay0, w01 = ax1*ay0;
            int r0 = yc0*WW;
            int o00 = ((r0 + xc0) << 5) + sub8;
            int o01 = ((r0 + xc1) << 5) + sub8;
            const float* q00 = vb[v] + o00;
            const float* q01 = vb[v] + o01;
            float4 t00a = *reinterpret_cast<const float4*>(q00);
            float4 t00b = *reinterpret_cast<const float4*>(q00 + 4);
            float4 t01a = *reinterpret_cast<const float4*>(q01);
            float4 t01b = *reinterpret_cast<const float4*>(q01 + 4);

            float blx = fmaf(w01, t01a.x, w00*t00a.x);
            float bly = fmaf(w01, t01a.y, w00*t00a.y);
            float blz = fmaf(w01, t01a.z, w00*t00a.z);
            float blw = fmaf(w01, t01a.w, w00*t00a.w);
            float acc = fmaf(rva.w,blw, fmaf(rva.z,blz, fmaf(rva.y,bly, rva.x*blx)));
            blx = fmaf(w01, t01b.x, w00*t00b.x);
            bly = fmaf(w01, t01b.y, w00*t00b.y);
            blz = fmaf(w01, t01b.z, w00*t00b.z);
            blw = fmaf(w01, t01b.w, w00*t00b.w);
            acc = fmaf(rvb.w,blw, fmaf(rvb.z,blz, fmaf(rvb.y,bly, fmaf(rvb.x,blx, acc))));

            if (ay1 != 0.f) {   // second tap row only when it has weight
                int yc1 = min(max(yi1, 0), HH-1);
                float w10 = ax0*ay1, w11 = ax1*ay1;
                int r1 = yc1*WW;
                int o10 = ((r1 + xc0) << 5) + sub8;
                int o11 = ((r1 + xc1) << 5) + sub8;
                const float* q10 = vb[v] + o10;
                const float* q11 = vb[v] + o11;
                float4 t10a = *reinterpret_cast<const float4*>(q10);
                float4 t10b = *reinterpret_cast<const float4*>(q10 + 4);
                float4 t11a = *reinterpret_cast<const float4*>(q11);
                float4 t11b = *reinterpret_cast<const float4*>(q11 + 4);
                float cx = fmaf(w11, t11a.x, w10*t10a.x);
                float cy = fmaf(w11, t11a.y, w10*t10a.y);
                float cz = fmaf(w11, t11a.z, w10*t10a.z);
                float cw = fmaf(w11, t11a.w, w10*t10a.w);
                acc = fmaf(rva.w,cw, fmaf(rva.z,cz, fmaf(rva.y,cy, fmaf(rva.x,cx, acc))));
                cx = fmaf(w11, t11b.x, w10*t10b.x);
                cy = fmaf(w11, t11b.y, w10*t10b.y);
                cz = fmaf(w11, t11b.z, w10*t10b.z);
                cw = fmaf(w11, t11b.w, w10*t10b.w);
                acc = fmaf(rvb.w,cw, fmaf(rvb.z,cz, fmaf(rvb.y,cy, fmaf(rvb.x,cx, acc))));
            }

            acc += __shfl_xor(acc, 1);
            acc += __shfl_xor(acc, 2);
            if (sub == 0) simL[v][dB][kpix] = acc * (1.f/(float)CC);
        }
    }
    __syncthreads();

    // ---- phase B: thread = (pixel p8, depth d2) ----
    int p8 = t >> 5;      // 0..7
    int d2 = t & 31;
    #pragma unroll
    for (int pi = 0; pi < PX/8; pi++) {
        int pidx = pi*8 + p8;
        int p = pbase + pidx;
        float s0 = simL[0][d2][pidx];
        float s1 = simL[1][d2][pidx];
        float s2 = simL[2][d2][pidx];
        float s3 = simL[3][d2][pidx];

        float m0 = half_max(mlp_h2(prm, s0));
        float m1 = half_max(mlp_h2(prm, s1));
        float m2 = half_max(mlp_h2(prm, s2));
        float m3 = half_max(mlp_h2(prm, s3));
        float vw0 = 1.f/(1.f + __expf(-m0));
        float vw1 = 1.f/(1.f + __expf(-m1));
        float vw2 = 1.f/(1.f + __expf(-m2));
        float vw3 = 1.f/(1.f + __expf(-m3));

        if (d2 == 0) out[OUT_VW + (b*NV + 0)*HWp + p] = vw0;
        if (d2 == 1) out[OUT_VW + (b*NV + 1)*HWp + p] = vw1;
        if (d2 == 2) out[OUT_VW + (b*NV + 2)*HWp + p] = vw2;
        if (d2 == 3) out[OUT_VW + (b*NV + 3)*HWp + p] = vw3;

        float wsum = 1e-5f + vw0 + vw1 + vw2 + vw3;
        float ssum = s0*vw0 + s1*vw1 + s2*vw2 + s3*vw3;
        simout[(b*DD + d2)*HWp + p] = ssum / wsum;
    }
}

// ---------------- 3x3x3 conv (SAME, zero pad) ----------------
__global__ __launch_bounds__(256) void conv_kernel(
    const float* __restrict__ sim, const float* __restrict__ rw,
    const float* __restrict__ rb, float* __restrict__ out) {
    int g = blockIdx.x*256 + threadIdx.x;   // B*D*HW
    int p = g % HWp;
    int dt = g / HWp;
    int d = dt % DD, b = dt / DD;
    int wi = p % WW, hi = p / WW;
    float acc = rb[0];
    #pragma unroll
    for (int kd = 0; kd < 3; kd++) {
        int dd2 = d + kd - 1;
        if (dd2 < 0 || dd2 >= DD) continue;
        #pragma unroll
        for (int kh = 0; kh < 3; kh++) {
            int hh2 = hi + kh - 1;
            if (hh2 < 0 || hh2 >= HH) continue;
            #pragma unroll
            for (int kw = 0; kw < 3; kw++) {
                int ww2 = wi + kw - 1;
                if (ww2 < 0 || ww2 >= WW) continue;
                acc += rw[(kd*3 + kh)*3 + kw] * sim[((b*DD + dd2)*HH + hh2)*WW + ww2];
            }
        }
    }
    out[OUT_COST + g] = acc;
}

// ---------------- softmax over D + argmax -> depth/conf/prob ----------------
__global__ __launch_bounds__(256) void softmax_kernel(
    const float* __restrict__ depthv, float* __restrict__ out) {
    int g = blockIdx.x*256 + threadIdx.x;   // B*HW
    int b = g / HWp, p = g % HWp;
    float c[DD];
    #pragma unroll
    for (int d = 0; d < DD; d++) c[d] = out[OUT_COST + (b*DD + d)*HWp + p];
    float m = c[0]; int bi = 0;
    #pragma unroll
    for (int d = 1; d < DD; d++) { if (c[d] > m) { m = c[d]; bi = d; } }
    float e[DD]; float sum = 0.f;
    #pragma unroll
    for (int d = 0; d < DD; d++) { e[d] = expf(c[d] - m); sum += e[d]; }
    float inv = 1.f / sum;
    #pragma unroll
    for (int d = 0; d < DD; d++) out[OUT_PROB + (b*DD + d)*HWp + p] = e[d] * inv;
    out[OUT_DEPTH + g] = depthv[(b*DD + bi)*HWp + p];
    out[OUT_CONF + g]  = inv;
}

extern "C" void kernel_launch(void* const* d_in, const int* in_sizes, int n_in,
                              void* d_out, int out_size, void* d_ws, size_t ws_size,
                              hipStream_t stream) {
    const float* features = (const float*)d_in[0];
    const float* proj     = (const float*)d_in[1];
    const float* depthv   = (const float*)d_in[2];
    const float* w0 = (const float*)d_in[4];
    const float* g0 = (const float*)d_in[5];
    const float* b0 = (const float*)d_in[6];
    const float* m0 = (const float*)d_in[7];
    const float* v0 = (const float*)d_in[8];
    const float* w1 = (const float*)d_in[9];
    const float* g1 = (const float*)d_in[10];
    const float* b1 = (const float*)d_in[11];
    const float* m1 = (const float*)d_in[12];
    const float* v1 = (const float*)d_in[13];
    const float* w2 = (const float*)d_in[14];
    const float* b2 = (const float*)d_in[15];
    const float* rw = (const float*)d_in[16];
    const float* rb = (const float*)d_in[17];
    float* out = (float*)d_out;
    float* ws  = (float*)d_ws;

    setup_kernel<<<1, 1, 0, stream>>>(proj, w0, g0, b0, m0, v0, w1, g1, b1, m1, v1, w2, b2, ws);
    transpose_kernel<<<VV*BB*HWp/256, 256, 0, stream>>>(features, ws + OFF_FEAT);

    fused_sim_kernel<<<dim3(HWp/PX, BB), 256, 0, stream>>>(
        ws + OFF_FEAT, ws + OFF_RT, ws + OFF_PRM, depthv,
        ws + OFF_SIM, out);

    conv_kernel<<<BB*DD*HWp/256, 256, 0, stream>>>(ws + OFF_SIM, rw, rb, out);
    softmax_kernel<<<BB*HWp/256, 256, 0, stream>>>(depthv, out);
}